// Round 6
// baseline (277.673 us; speedup 1.0000x reference)
//
#include <hip/hip_runtime.h>
#include <math.h>

#define DIM    96
#define HEADS  3
#define NTOK   49
#define NWIN   64
#define SCALE  0.17677669529663687f
#define MW     2          // windows per block

// ---- workspace layout (bytes) ----
// MODE 2: qkv_wb bf16 @0 (55296) | proj_wb bf16 @55296 (18432) | tabT [64][3][49k][49q] f32 @73728
// MODE 1: qkv_wb bf16 @0         | proj_wb bf16 @55296         | biasT [3][49k][49q] f32 @73728
// MODE 0: biasT [3][49k][49q] f32 @0 (28812)
#define PROJWB_OFFB 55296
#define TAB_OFFB    73728
#define FUSED_TAB_ELEMS (NWIN * HEADS * NTOK * NTOK)
#define BIAS_TAB_ELEMS  (HEADS * NTOK * NTOK)
#define WS_MODE2_NEED (TAB_OFFB + FUSED_TAB_ELEMS * 4)
#define WS_MODE1_NEED (TAB_OFFB + BIAS_TAB_ELEMS * 4)

// ---- LDS (short indices), XOR-swizzled, per-HEAD double-buffered ----
// buffer b @ b*8192; window w @ +w*4096; K_h [64][32] @+0 (2048 sh); VT_h [32][64] @+2048
// total 16384 sh = 32768 B -> 5 blocks/CU by LDS
#define BUFSTRIDE 8192
#define WSTRIDE   4096
#define VT_OFF    2048
#define LDS_SHORTS (2 * BUFSTRIDE)

typedef float  f32x4   __attribute__((ext_vector_type(4)));
typedef __bf16 bf16x8  __attribute__((ext_vector_type(8)));
typedef short  short8  __attribute__((ext_vector_type(8)));
typedef __bf16 bf16x4  __attribute__((ext_vector_type(4)));
typedef short  short4v __attribute__((ext_vector_type(4)));

union U8 { short8  s; bf16x8 b; };
union U4 { short4v s; bf16x4 b; };

// XOR-swizzle on short index: XOR 16B-granule bits [5:3] with 128B-line bits [8:6].
// All region bases are 512-short aligned.
__device__ __forceinline__ int swz(int s) { return s ^ ((s >> 3) & 56); }

__device__ __forceinline__ unsigned short f2bf(float f) {
    __bf16 h = (__bf16)f;
    union { __bf16 h; unsigned short u; } v; v.h = h; return v.u;
}

__device__ __forceinline__ void ldcvt_g(const float* __restrict__ p, U8& u) {
    float4 f0 = *(const float4*)p;
    float4 f1 = *(const float4*)(p + 4);
    u.b[0] = (__bf16)f0.x; u.b[1] = (__bf16)f0.y; u.b[2] = (__bf16)f0.z; u.b[3] = (__bf16)f0.w;
    u.b[4] = (__bf16)f1.x; u.b[5] = (__bf16)f1.y; u.b[6] = (__bf16)f1.z; u.b[7] = (__bf16)f1.w;
}

// ---- prepass: bf16 weights + TRANSPOSED (bias+mask | bias) table tabT[..][k][q] ----
__global__ __launch_bounds__(256)
void prep(const float* __restrict__ rpb, const int* __restrict__ rel,
          const float* __restrict__ mask,
          const float* __restrict__ qkv_w, const float* __restrict__ proj_w,
          unsigned short* __restrict__ qkv_wb, unsigned short* __restrict__ proj_wb,
          float* __restrict__ tab, int mode)
{
    int t = blockIdx.x * 256 + threadIdx.x;
    if (mode >= 1) {
        if (t < 3 * DIM * DIM) qkv_wb[t] = f2bf(qkv_w[t]);
        if (t < DIM * DIM)     proj_wb[t] = f2bf(proj_w[t]);
    }
    if (mode == 2) {
        if (t < FUSED_TAB_ELEMS) {
            int win = t / (HEADS * NTOK * NTOK);
            int rem = t - win * (HEADS * NTOK * NTOK);
            int h   = rem / (NTOK * NTOK);
            int ij  = rem - h * (NTOK * NTOK);
            int k = ij / NTOK, q = ij - k * NTOK;
            tab[t] = rpb[rel[q * NTOK + k] * HEADS + h] + mask[win * (NTOK * NTOK) + q * NTOK + k];
        }
    } else if (t < BIAS_TAB_ELEMS) {
        int h = t / (NTOK * NTOK), ij = t - h * (NTOK * NTOK);
        int k = ij / NTOK, q = ij - k * NTOK;
        tab[t] = rpb[rel[q * NTOK + k] * HEADS + h];
    }
}

// x32 A-frag weight load (16B)
template<int MODE>
__device__ __forceinline__ void ldw(const unsigned short* __restrict__ wb,
                                    const float* __restrict__ wf, int idx, U8& u) {
    if constexpr (MODE >= 1) u.s = *(const short8*)(wb + idx);
    else                     ldcvt_g(wf + idx, u);
}
// x16 frag load (8B)
template<int MODE>
__device__ __forceinline__ void ldw4(const unsigned short* __restrict__ wb,
                                     const float* __restrict__ wf, int idx, U4& u) {
    if constexpr (MODE >= 1) u.s = *(const short4v*)(wb + idx);
    else {
        float4 f = *(const float4*)(wf + idx);
        u.b[0] = (__bf16)f.x; u.b[1] = (__bf16)f.y; u.b[2] = (__bf16)f.z; u.b[3] = (__bf16)f.w;
    }
}

template<int MODE>
__global__ __launch_bounds__(256, 4)
void winattn(const float* __restrict__ x,
             const float* __restrict__ mask,
             const float* __restrict__ qkv_w,
             const float* __restrict__ qkv_b,
             const float* __restrict__ proj_w,
             const float* __restrict__ proj_b,
             const unsigned short* __restrict__ qkv_wb,
             const unsigned short* __restrict__ proj_wb,
             const float* __restrict__ tab,
             float* __restrict__ out, int nwin_tot)
{
    __shared__ __align__(16) unsigned short sbuf[LDS_SHORTS];

    const int tid  = threadIdx.x;
    const int lane = tid & 63;
    const int wave = __builtin_amdgcn_readfirstlane(tid >> 6);
    const int l15  = lane & 15;
    const int quad = lane >> 4;
    const int tokg = 16 * wave + l15;
    const int qcl  = (tokg < NTOK) ? tokg : (NTOK - 1);

    int bw[MW];
    const float* fmh[MW][3];
    const float* mww[MW];
    #pragma unroll
    for (int w = 0; w < MW; ++w) {
        int b = blockIdx.x * MW + w;
        bw[w] = (b < nwin_tot) ? b : (nwin_tot - 1);
        const int win = bw[w] & (NWIN - 1);
        #pragma unroll
        for (int h = 0; h < 3; ++h)
            fmh[w][h] = (MODE == 2) ? (tab + (size_t)(win * HEADS + h) * (NTOK * NTOK))
                                    : (tab + h * (NTOK * NTOK));
        mww[w] = mask + (size_t)win * (NTOK * NTOK);
    }

    // ---- x A-frags for both windows ----
    U8 af[MW][3];
    #pragma unroll
    for (int w = 0; w < MW; ++w) {
        const float* xw = x + (size_t)bw[w] * (NTOK * DIM);
        #pragma unroll
        for (int s = 0; s < 3; ++s) {
            if (tokg < NTOK) ldcvt_g(xw + tokg * DIM + 32 * s + quad * 8, af[w][s]);
            else {
                #pragma unroll
                for (int j = 0; j < 8; ++j) af[w][s].b[j] = (__bf16)0.0f;
            }
        }
    }

    // Q B-frags, double-buffered by head parity
    U4 qB[2][MW][2];

    // ---- stage(): compute Q_h -> regs, K_h/VT_h -> LDS buf hb, for all MW windows ----
    // tiles: {Q:2h,2h+1, K:6+2h,7+2h, V:12+2h,13+2h}, depth-2 ping-pong weight prefetch
    auto stage = [&](const int h, const int hb) {
        const int tl[6] = {2*h, 2*h + 1, 6 + 2*h, 7 + 2*h, 12 + 2*h, 13 + 2*h};
        const int bb = hb * BUFSTRIDE;
        U8 wpf[2][3];
        f32x4 qbp[2];
        #pragma unroll
        for (int s = 0; s < 3; ++s) {
            ldw<MODE>(qkv_wb, qkv_w, (16 * tl[0] + l15) * DIM + 32 * s + quad * 8, wpf[0][s]);
            ldw<MODE>(qkv_wb, qkv_w, (16 * tl[1] + l15) * DIM + 32 * s + quad * 8, wpf[1][s]);
        }
        qbp[0] = *(const f32x4*)(qkv_b + 16 * tl[0] + quad * 4);
        qbp[1] = *(const f32x4*)(qkv_b + 16 * tl[1] + quad * 4);
        #pragma unroll
        for (int i = 0; i < 6; ++i) {
            f32x4 acc[MW];
            #pragma unroll
            for (int w = 0; w < MW; ++w) {
                f32x4 z = {0.f, 0.f, 0.f, 0.f};
                #pragma unroll
                for (int s = 0; s < 3; ++s)
                    z = __builtin_amdgcn_mfma_f32_16x16x32_bf16(wpf[i & 1][s].b, af[w][s].b, z, 0, 0, 0);
                acc[w] = z;
            }
            const f32x4 qb = qbp[i & 1];
            if (i + 2 < 6) {
                #pragma unroll
                for (int s = 0; s < 3; ++s)
                    ldw<MODE>(qkv_wb, qkv_w, (16 * tl[i + 2] + l15) * DIM + 32 * s + quad * 8, wpf[i & 1][s]);
                qbp[i & 1] = *(const f32x4*)(qkv_b + 16 * tl[i + 2] + quad * 4);
            }
            if (i < 2) {               // Q -> registers (d-chunk i)
                #pragma unroll
                for (int w = 0; w < MW; ++w)
                    #pragma unroll
                    for (int r = 0; r < 4; ++r)
                        qB[hb][w][i].b[r] = (__bf16)((acc[w][r] + qb[r]) * SCALE);
            } else if (i < 4) {        // K -> LDS token-major, packed b64
                const int dc = i - 2;
                #pragma unroll
                for (int w = 0; w < MW; ++w) {
                    U4 pk;
                    #pragma unroll
                    for (int r = 0; r < 4; ++r) pk.b[r] = (__bf16)(acc[w][r] + qb[r]);
                    *(short4v*)(sbuf + swz(bb + w * WSTRIDE + tokg * 32 + dc * 16 + quad * 4)) = pk.s;
                }
            } else {                   // V -> LDS d-major scatter
                const int dc = i - 4;
                #pragma unroll
                for (int w = 0; w < MW; ++w)
                    #pragma unroll
                    for (int r = 0; r < 4; ++r)
                        sbuf[swz(bb + w * WSTRIDE + VT_OFF + (dc * 16 + quad * 4 + r) * 64 + tokg)] =
                            f2bf(acc[w][r] + qb[r]);
            }
        }
    };

    stage(0, 0);

    // prefetch tab for iteration 0 (h=0,w=0); hides under the barrier drain
    float tv[2][4][4];
    #pragma unroll
    for (int t = 0; t < 4; ++t)
        #pragma unroll
        for (int r = 0; r < 4; ++r) {
            const int k = 16 * t + quad * 4 + r;
            float v = fmh[0][0][k * NTOK + qcl];
            if constexpr (MODE != 2) {
                const int kcl = (k < NTOK) ? k : (NTOK - 1);
                v += mww[0][qcl * NTOK + kcl];
            }
            tv[0][t][r] = v;
        }

    __syncthreads();   // buf0 (head 0) visible

    // ====== Phase 2+3: per (head, window); stage(h+1) overlapped with h's softmax ======
    U4 oB[MW][3][2];
    #pragma unroll
    for (int h = 0; h < 3; ++h) {
        const int rb = (h & 1) * BUFSTRIDE;
        #pragma unroll
        for (int w = 0; w < MW; ++w) {
            const int it = h * MW + w;
            const int base = rb + w * WSTRIDE;
            f32x4 st[4];
            #pragma unroll
            for (int t = 0; t < 4; ++t) {
                U4 k0, k1;
                k0.s = *(const short4v*)(sbuf + swz(base + (16 * t + l15) * 32 + quad * 4));
                k1.s = *(const short4v*)(sbuf + swz(base + (16 * t + l15) * 32 + 16 + quad * 4));
                f32x4 z = {0.f, 0.f, 0.f, 0.f};
                z = __builtin_amdgcn_mfma_f32_16x16x16bf16_1k(k0.s, qB[h & 1][w][0].s, z, 0, 0, 0);
                z = __builtin_amdgcn_mfma_f32_16x16x16bf16_1k(k1.s, qB[h & 1][w][1].s, z, 0, 0, 0);
                st[t] = z;
            }
            // overlap next head's staging (weight loads + MFMAs + LDS writes) with softmax
            if (w == 0 && h < 2) stage(h + 1, (h + 1) & 1);
            // prefetch next iteration's tab
            if (it < 3 * MW - 1) {
                const int hn = (it + 1) / MW, wn = (it + 1) % MW;
                #pragma unroll
                for (int t = 0; t < 4; ++t)
                    #pragma unroll
                    for (int r = 0; r < 4; ++r) {
                        const int k = 16 * t + quad * 4 + r;
                        float v = fmh[wn][hn][k * NTOK + qcl];
                        if constexpr (MODE != 2) {
                            const int kcl = (k < NTOK) ? k : (NTOK - 1);
                            v += mww[wn][qcl * NTOK + kcl];
                        }
                        tv[(it + 1) & 1][t][r] = v;
                    }
            }
            // in-lane neg-softmax: lane holds S^T[k=16t+quad*4+r][q=tokg]
            float sval[4][4];
            float mx = -1e30f;
            #pragma unroll
            for (int t = 0; t < 4; ++t)
                #pragma unroll
                for (int r = 0; r < 4; ++r) {
                    const int k = 16 * t + quad * 4 + r;
                    float s_ = st[t][r] + tv[it & 1][t][r];
                    sval[t][r] = s_;
                    if (k < NTOK) mx = fmaxf(mx, fabsf(s_));
                }
            mx = fmaxf(mx, __shfl_xor(mx, 16));
            mx = fmaxf(mx, __shfl_xor(mx, 32));
            float sm = 0.f;
            U4 pa[4];
            #pragma unroll
            for (int t = 0; t < 4; ++t)
                #pragma unroll
                for (int r = 0; r < 4; ++r) {
                    const int k = 16 * t + quad * 4 + r;
                    const float s_ = sval[t][r];
                    const float e = (k < NTOK) ? __expf(fabsf(s_) - mx) : 0.f;
                    sm += e;
                    pa[t].b[r] = (__bf16)((s_ > 0.f) ? e : ((s_ < 0.f) ? -e : 0.f));
                }
            sm += __shfl_xor(sm, 16);
            sm += __shfl_xor(sm, 32);
            const float invl = 1.f / sm;
            // O^T = sum_t mfma16(VT-chunk, P)
            #pragma unroll
            for (int dp = 0; dp < 2; ++dp) {
                f32x4 o = {0.f, 0.f, 0.f, 0.f};
                #pragma unroll
                for (int t = 0; t < 4; ++t) {
                    U4 vf;
                    vf.s = *(const short4v*)(sbuf + swz(base + VT_OFF + (16 * dp + l15) * 64 + 16 * t + quad * 4));
                    o = __builtin_amdgcn_mfma_f32_16x16x16bf16_1k(vf.s, pa[t].s, o, 0, 0, 0);
                }
                #pragma unroll
                for (int r = 0; r < 4; ++r)
                    oB[w][h][dp].b[r] = (__bf16)(o[r] * invl);
            }
        }
        if (h < 2) __syncthreads();   // next buf staged + this buf's reads done
    }

    // ================= Phase 4: out^T = mfma16(proj_w, O), batched+pingpong weights =================
    {
        U4 w4pf[2][6];
        f32x4 pbp[2];
        #pragma unroll
        for (int kc = 0; kc < 6; ++kc)
            ldw4<MODE>(proj_wb, proj_w, l15 * DIM + 16 * kc + quad * 4, w4pf[0][kc]);
        pbp[0] = *(const f32x4*)(proj_b + quad * 4);

        #pragma unroll
        for (int tc = 0; tc < 6; ++tc) {
            if (tc + 1 < 6) {
                #pragma unroll
                for (int kc = 0; kc < 6; ++kc)
                    ldw4<MODE>(proj_wb, proj_w, (16 * (tc + 1) + l15) * DIM + 16 * kc + quad * 4,
                               w4pf[(tc + 1) & 1][kc]);
                pbp[(tc + 1) & 1] = *(const f32x4*)(proj_b + 16 * (tc + 1) + quad * 4);
            }
            f32x4 acc[MW];
            #pragma unroll
            for (int w = 0; w < MW; ++w) acc[w] = f32x4{0.f, 0.f, 0.f, 0.f};
            #pragma unroll
            for (int kc = 0; kc < 6; ++kc)
                #pragma unroll
                for (int w = 0; w < MW; ++w)
                    acc[w] = __builtin_amdgcn_mfma_f32_16x16x16bf16_1k(
                        w4pf[tc & 1][kc].s, oB[w][kc >> 1][kc & 1].s, acc[w], 0, 0, 0);
            const f32x4 pb = pbp[tc & 1];
            #pragma unroll
            for (int w = 0; w < MW; ++w) {
                if (tokg < NTOK)
                    *(f32x4*)(out + (size_t)bw[w] * (NTOK * DIM) + tokg * DIM + 16 * tc + quad * 4) =
                        acc[w] + pb;
            }
        }
    }
}

extern "C" void kernel_launch(void* const* d_in, const int* in_sizes, int n_in,
                              void* d_out, int out_size, void* d_ws, size_t ws_size,
                              hipStream_t stream) {
    const float* x      = (const float*)d_in[0];
    const float* mask   = (const float*)d_in[1];
    const float* qkv_w  = (const float*)d_in[2];
    const float* qkv_b  = (const float*)d_in[3];
    const float* proj_w = (const float*)d_in[4];
    const float* proj_b = (const float*)d_in[5];
    const float* rpb    = (const float*)d_in[6];
    const int*   rel    = (const int*)d_in[7];
    float* outp         = (float*)d_out;

    int mode;
    if      (ws_size >= (size_t)WS_MODE2_NEED) mode = 2;
    else if (ws_size >= (size_t)WS_MODE1_NEED) mode = 1;
    else                                        mode = 0;

    unsigned short* qkv_wb  = (unsigned short*)d_ws;
    unsigned short* proj_wb = (unsigned short*)((char*)d_ws + PROJWB_OFFB);
    float* tab = (mode >= 1) ? (float*)((char*)d_ws + TAB_OFFB) : (float*)d_ws;

    const int npre = (mode == 2) ? FUSED_TAB_ELEMS
                   : (mode == 1) ? 3 * DIM * DIM
                                 : BIAS_TAB_ELEMS;
    prep<<<(npre + 255) / 256, 256, 0, stream>>>(rpb, rel, mask, qkv_w, proj_w,
                                                 qkv_wb, proj_wb, tab, mode);

    const int n_windows = in_sizes[0] / (NTOK * DIM);   // 4096
    const int nb = (n_windows + MW - 1) / MW;
    if (mode == 2)
        winattn<2><<<nb, 256, 0, stream>>>(x, mask, qkv_w, qkv_b, proj_w, proj_b,
                                           qkv_wb, proj_wb, tab, outp, n_windows);
    else if (mode == 1)
        winattn<1><<<nb, 256, 0, stream>>>(x, mask, qkv_w, qkv_b, proj_w, proj_b,
                                           qkv_wb, proj_wb, tab, outp, n_windows);
    else
        winattn<0><<<nb, 256, 0, stream>>>(x, mask, qkv_w, qkv_b, proj_w, proj_b,
                                           qkv_wb, proj_wb, tab, outp, n_windows);
}

// Round 7
// 275.511 us; speedup vs baseline: 1.0078x; 1.0078x over previous
//
#include <hip/hip_runtime.h>
#include <math.h>

#define DIM    96
#define HEADS  3
#define NTOK   49
#define NWIN   64
#define SCALE  0.17677669529663687f
#define MW     2          // windows per block

// ---- workspace layout (bytes) ----
// MODE 2: qkv_wb bf16 @0 (55296) | proj_wb bf16 @55296 (18432) | tab [64][3][49q][64k] f32 @73728 (2408448)
// MODE 1: qkv_wb bf16 @0         | proj_wb bf16 @55296         | tab [3][49q][64k] f32 @73728 (37632)
// MODE 0: bias [3][49q][49k] f32 @0 (28812)
#define PROJWB_OFFB 55296
#define TAB_OFFB    73728
#define PAD_FUSED_ELEMS (NWIN * HEADS * NTOK * 64)
#define PAD_BIAS_ELEMS  (HEADS * NTOK * 64)
#define BIAS_TAB_ELEMS  (HEADS * NTOK * NTOK)
#define WS_MODE2_NEED (TAB_OFFB + PAD_FUSED_ELEMS * 4)
#define WS_MODE1_NEED (TAB_OFFB + PAD_BIAS_ELEMS * 4)

// ---- LDS (short indices), XOR-swizzled, per-HEAD double-buffered ----
// buffer b @ b*8192; window w @ +w*4096; K_h [64][32] @+0 (2048 sh); VT_h [32][64] @+2048
// total 16384 sh = 32768 B -> up to 5 blocks/CU by LDS
#define BUFSTRIDE 8192
#define WSTRIDE   4096
#define VT_OFF    2048
#define LDS_SHORTS (2 * BUFSTRIDE)

typedef float  f32x4   __attribute__((ext_vector_type(4)));
typedef __bf16 bf16x8  __attribute__((ext_vector_type(8)));
typedef short  short8  __attribute__((ext_vector_type(8)));
typedef __bf16 bf16x4  __attribute__((ext_vector_type(4)));
typedef short  short4v __attribute__((ext_vector_type(4)));

union U8 { short8  s; bf16x8 b; };
union U4 { short4v s; bf16x4 b; };

// XOR-swizzle on short index: XOR 16B-granule bits [5:3] with 128B-line bits [8:6].
__device__ __forceinline__ int swz(int s) { return s ^ ((s >> 3) & 56); }

__device__ __forceinline__ unsigned short f2bf(float f) {
    __bf16 h = (__bf16)f;
    union { __bf16 h; unsigned short u; } v; v.h = h; return v.u;
}

__device__ __forceinline__ void ldcvt_g(const float* __restrict__ p, U8& u) {
    float4 f0 = *(const float4*)p;
    float4 f1 = *(const float4*)(p + 4);
    u.b[0] = (__bf16)f0.x; u.b[1] = (__bf16)f0.y; u.b[2] = (__bf16)f0.z; u.b[3] = (__bf16)f0.w;
    u.b[4] = (__bf16)f1.x; u.b[5] = (__bf16)f1.y; u.b[6] = (__bf16)f1.z; u.b[7] = (__bf16)f1.w;
}

// ---- prepass: bf16 weights + [q][k]-oriented padded (bias+mask | bias) table ----
__global__ __launch_bounds__(256)
void prep(const float* __restrict__ rpb, const int* __restrict__ rel,
          const float* __restrict__ mask,
          const float* __restrict__ qkv_w, const float* __restrict__ proj_w,
          unsigned short* __restrict__ qkv_wb, unsigned short* __restrict__ proj_wb,
          float* __restrict__ tab, int mode)
{
    int t = blockIdx.x * 256 + threadIdx.x;
    if (mode >= 1) {
        if (t < 3 * DIM * DIM) qkv_wb[t] = f2bf(qkv_w[t]);
        if (t < DIM * DIM)     proj_wb[t] = f2bf(proj_w[t]);
    }
    if (mode == 2) {
        if (t < PAD_FUSED_ELEMS) {
            int win = t / (HEADS * NTOK * 64);
            int rem = t - win * (HEADS * NTOK * 64);
            int h   = rem / (NTOK * 64);
            int ij  = rem - h * (NTOK * 64);
            int q = ij >> 6, k = ij & 63;
            tab[t] = (k < NTOK)
                ? rpb[rel[q * NTOK + k] * HEADS + h] + mask[win * (NTOK * NTOK) + q * NTOK + k]
                : 0.f;
        }
    } else if (mode == 1) {
        if (t < PAD_BIAS_ELEMS) {
            int h = t / (NTOK * 64), ij = t - h * (NTOK * 64);
            int q = ij >> 6, k = ij & 63;
            tab[t] = (k < NTOK) ? rpb[rel[q * NTOK + k] * HEADS + h] : 0.f;
        }
    } else {
        if (t < BIAS_TAB_ELEMS) {
            int h = t / (NTOK * NTOK), ij = t - h * (NTOK * NTOK);
            int q = ij / NTOK, k = ij - q * NTOK;
            tab[t] = rpb[rel[q * NTOK + k] * HEADS + h];
        }
    }
}

// x32 A-frag weight load (16B)
template<int MODE>
__device__ __forceinline__ void ldw(const unsigned short* __restrict__ wb,
                                    const float* __restrict__ wf, int idx, U8& u) {
    if constexpr (MODE >= 1) u.s = *(const short8*)(wb + idx);
    else                     ldcvt_g(wf + idx, u);
}
// x16 frag load (8B)
template<int MODE>
__device__ __forceinline__ void ldw4(const unsigned short* __restrict__ wb,
                                     const float* __restrict__ wf, int idx, U4& u) {
    if constexpr (MODE >= 1) u.s = *(const short4v*)(wb + idx);
    else {
        float4 f = *(const float4*)(wf + idx);
        u.b[0] = (__bf16)f.x; u.b[1] = (__bf16)f.y; u.b[2] = (__bf16)f.z; u.b[3] = (__bf16)f.w;
    }
}

// tab fetch for one (head,window): 4 x f32x4 (MODE>=1, padded pitch 64) or scalars (MODE 0)
template<int MODE>
__device__ __forceinline__ void tab_fetch(f32x4 (&dst)[4],
                                          const float* __restrict__ fm,
                                          const float* __restrict__ mw,
                                          const int quad, const int qcl)
{
    #pragma unroll
    for (int t = 0; t < 4; ++t) {
        if constexpr (MODE >= 1) {
            f32x4 v = *(const f32x4*)(fm + qcl * 64 + 16 * t + quad * 4);
            if constexpr (MODE == 1) {
                #pragma unroll
                for (int r = 0; r < 4; ++r) {
                    const int k = 16 * t + quad * 4 + r;
                    const int kcl = (k < NTOK) ? k : (NTOK - 1);
                    v[r] += mw[qcl * NTOK + kcl];
                }
            }
            dst[t] = v;
        } else {
            f32x4 v;
            #pragma unroll
            for (int r = 0; r < 4; ++r) {
                const int k = 16 * t + quad * 4 + r;
                const int kcl = (k < NTOK) ? k : (NTOK - 1);
                v[r] = fm[qcl * NTOK + kcl] + mw[qcl * NTOK + kcl];
            }
            dst[t] = v;
        }
    }
}

// ---- stage head H into LDS buffer HB (+ Q -> qB[HB]); ALL indexing compile-time ----
template<int MODE, int H, int HB>
__device__ __forceinline__ void stage_head(
    unsigned short* __restrict__ sbuf,
    const U8 (&af)[MW][3],
    U4 (&qB)[2][MW][2],
    const unsigned short* __restrict__ qkv_wb,
    const float* __restrict__ qkv_w,
    const float* __restrict__ qkv_b,
    const int l15, const int quad, const int tokg)
{
    constexpr int BB = HB * BUFSTRIDE;
    U8 wpf[2][3];
    f32x4 qbp[2];
    #pragma unroll
    for (int s = 0; s < 3; ++s) {
        ldw<MODE>(qkv_wb, qkv_w, (16 * (2 * H + 0) + l15) * DIM + 32 * s + quad * 8, wpf[0][s]);
        ldw<MODE>(qkv_wb, qkv_w, (16 * (2 * H + 1) + l15) * DIM + 32 * s + quad * 8, wpf[1][s]);
    }
    qbp[0] = *(const f32x4*)(qkv_b + 16 * (2 * H + 0) + quad * 4);
    qbp[1] = *(const f32x4*)(qkv_b + 16 * (2 * H + 1) + quad * 4);
    #pragma unroll
    for (int i = 0; i < 6; ++i) {
        f32x4 acc[MW];
        #pragma unroll
        for (int w = 0; w < MW; ++w) {
            f32x4 z = {0.f, 0.f, 0.f, 0.f};
            #pragma unroll
            for (int s = 0; s < 3; ++s)
                z = __builtin_amdgcn_mfma_f32_16x16x32_bf16(wpf[i & 1][s].b, af[w][s].b, z, 0, 0, 0);
            acc[w] = z;
        }
        const f32x4 qb = qbp[i & 1];
        if (i + 2 < 6) {   // prefetch next tile's weights (K tiles 6+2H.., V tiles 12+2H..)
            const int nt = (i + 2 < 4) ? (4 + 2 * H + (i + 2)) : (8 + 2 * H + (i + 2));
            #pragma unroll
            for (int s = 0; s < 3; ++s)
                ldw<MODE>(qkv_wb, qkv_w, (16 * nt + l15) * DIM + 32 * s + quad * 8, wpf[i & 1][s]);
            qbp[i & 1] = *(const f32x4*)(qkv_b + 16 * nt + quad * 4);
        }
        if (i < 2) {               // Q -> registers (d-chunk i)
            #pragma unroll
            for (int w = 0; w < MW; ++w)
                #pragma unroll
                for (int r = 0; r < 4; ++r)
                    qB[HB][w][i].b[r] = (__bf16)((acc[w][r] + qb[r]) * SCALE);
        } else if (i < 4) {        // K -> LDS token-major, packed b64
            const int dc = i - 2;
            #pragma unroll
            for (int w = 0; w < MW; ++w) {
                U4 pk;
                #pragma unroll
                for (int r = 0; r < 4; ++r) pk.b[r] = (__bf16)(acc[w][r] + qb[r]);
                *(short4v*)(sbuf + swz(BB + w * WSTRIDE + tokg * 32 + dc * 16 + quad * 4)) = pk.s;
            }
        } else {                   // V -> LDS d-major scatter
            const int dc = i - 4;
            #pragma unroll
            for (int w = 0; w < MW; ++w)
                #pragma unroll
                for (int r = 0; r < 4; ++r)
                    sbuf[swz(BB + w * WSTRIDE + VT_OFF + (dc * 16 + quad * 4 + r) * 64 + tokg)] =
                        f2bf(acc[w][r] + qb[r]);
        }
    }
}

// ---- attention for head H (reads buf H&1); stages head H+1 overlapped with softmax ----
template<int MODE, int H>
__device__ __forceinline__ void attn_head(
    unsigned short* __restrict__ sbuf,
    const U8 (&af)[MW][3],
    U4 (&qB)[2][MW][2],
    U4 (&oB)[MW][HEADS][2],
    f32x4 (&tv)[2][4],
    const float* const (&fmh)[MW][HEADS],
    const float* const (&mww)[MW],
    const unsigned short* __restrict__ qkv_wb,
    const float* __restrict__ qkv_w,
    const float* __restrict__ qkv_b,
    const int l15, const int quad, const int tokg, const int qcl)
{
    constexpr int RB = (H & 1) * BUFSTRIDE;
    #pragma unroll
    for (int w = 0; w < MW; ++w) {
        const int base = RB + w * WSTRIDE;
        f32x4 st[4];
        #pragma unroll
        for (int t = 0; t < 4; ++t) {
            U4 k0, k1;
            k0.s = *(const short4v*)(sbuf + swz(base + (16 * t + l15) * 32 + quad * 4));
            k1.s = *(const short4v*)(sbuf + swz(base + (16 * t + l15) * 32 + 16 + quad * 4));
            f32x4 z = {0.f, 0.f, 0.f, 0.f};
            z = __builtin_amdgcn_mfma_f32_16x16x16bf16_1k(k0.s, qB[H & 1][w][0].s, z, 0, 0, 0);
            z = __builtin_amdgcn_mfma_f32_16x16x16bf16_1k(k1.s, qB[H & 1][w][1].s, z, 0, 0, 0);
            st[t] = z;
        }
        // overlap next head's staging with this head's softmax (compile-time head ids)
        if constexpr (H < 2) {
            if (w == 0)
                stage_head<MODE, H + 1, (H + 1) & 1>(sbuf, af, qB, qkv_wb, qkv_w, qkv_b,
                                                     l15, quad, tokg);
        }
        // prefetch next iteration's tab (4 x f32x4)
        if (H * MW + w + 1 < HEADS * MW) {
            const int itn = H * MW + w + 1;
            tab_fetch<MODE>(tv[itn & 1], fmh[itn % MW][itn / MW], mww[itn % MW], quad, qcl);
        }
        // in-lane neg-softmax: lane holds S^T[k=16t+quad*4+r][q=tokg]
        const int it = H * MW + w;
        float sval[4][4];
        float mx = -1e30f;
        #pragma unroll
        for (int t = 0; t < 4; ++t)
            #pragma unroll
            for (int r = 0; r < 4; ++r) {
                const int k = 16 * t + quad * 4 + r;
                float s_ = st[t][r] + tv[it & 1][t][r];
                sval[t][r] = s_;
                if (k < NTOK) mx = fmaxf(mx, fabsf(s_));
            }
        mx = fmaxf(mx, __shfl_xor(mx, 16));
        mx = fmaxf(mx, __shfl_xor(mx, 32));
        float sm = 0.f;
        U4 pa[4];
        #pragma unroll
        for (int t = 0; t < 4; ++t)
            #pragma unroll
            for (int r = 0; r < 4; ++r) {
                const int k = 16 * t + quad * 4 + r;
                const float s_ = sval[t][r];
                const float e = (k < NTOK) ? __expf(fabsf(s_) - mx) : 0.f;
                sm += e;
                pa[t].b[r] = (__bf16)((s_ > 0.f) ? e : ((s_ < 0.f) ? -e : 0.f));
            }
        sm += __shfl_xor(sm, 16);
        sm += __shfl_xor(sm, 32);
        const float invl = 1.f / sm;
        // O^T = sum_t mfma16(VT-chunk, P)
        #pragma unroll
        for (int dp = 0; dp < 2; ++dp) {
            f32x4 o = {0.f, 0.f, 0.f, 0.f};
            #pragma unroll
            for (int t = 0; t < 4; ++t) {
                U4 vf;
                vf.s = *(const short4v*)(sbuf + swz(base + VT_OFF + (16 * dp + l15) * 64 + 16 * t + quad * 4));
                o = __builtin_amdgcn_mfma_f32_16x16x16bf16_1k(vf.s, pa[t].s, o, 0, 0, 0);
            }
            #pragma unroll
            for (int r = 0; r < 4; ++r)
                oB[w][H][dp].b[r] = (__bf16)(o[r] * invl);
        }
    }
}

template<int MODE>
__global__ __launch_bounds__(256, 4)
void winattn(const float* __restrict__ x,
             const float* __restrict__ mask,
             const float* __restrict__ qkv_w,
             const float* __restrict__ qkv_b,
             const float* __restrict__ proj_w,
             const float* __restrict__ proj_b,
             const unsigned short* __restrict__ qkv_wb,
             const unsigned short* __restrict__ proj_wb,
             const float* __restrict__ tab,
             float* __restrict__ out, int nwin_tot)
{
    __shared__ __align__(16) unsigned short sbuf[LDS_SHORTS];

    const int tid  = threadIdx.x;
    const int lane = tid & 63;
    const int wave = __builtin_amdgcn_readfirstlane(tid >> 6);
    const int l15  = lane & 15;
    const int quad = lane >> 4;
    const int tokg = 16 * wave + l15;
    const int qcl  = (tokg < NTOK) ? tokg : (NTOK - 1);

    int bw[MW];
    const float* fmh[MW][HEADS];
    const float* mww[MW];
    #pragma unroll
    for (int w = 0; w < MW; ++w) {
        int b = blockIdx.x * MW + w;
        bw[w] = (b < nwin_tot) ? b : (nwin_tot - 1);
        const int win = bw[w] & (NWIN - 1);
        #pragma unroll
        for (int h = 0; h < HEADS; ++h)
            fmh[w][h] = (MODE == 2) ? (tab + (size_t)((win * HEADS + h) * NTOK) * 64)
                      : (MODE == 1) ? (tab + (size_t)(h * NTOK) * 64)
                                    : (tab + (size_t)h * NTOK * NTOK);
        mww[w] = mask + (size_t)win * (NTOK * NTOK);
    }

    // ---- x A-frags for both windows ----
    U8 af[MW][3];
    #pragma unroll
    for (int w = 0; w < MW; ++w) {
        const float* xw = x + (size_t)bw[w] * (NTOK * DIM);
        #pragma unroll
        for (int s = 0; s < 3; ++s) {
            if (tokg < NTOK) ldcvt_g(xw + tokg * DIM + 32 * s + quad * 8, af[w][s]);
            else {
                #pragma unroll
                for (int j = 0; j < 8; ++j) af[w][s].b[j] = (__bf16)0.0f;
            }
        }
    }

    U4 qB[2][MW][2];
    U4 oB[MW][HEADS][2];
    f32x4 tv[2][4];

    stage_head<MODE, 0, 0>(sbuf, af, qB, qkv_wb, qkv_w, qkv_b, l15, quad, tokg);
    tab_fetch<MODE>(tv[0], fmh[0][0], mww[0], quad, qcl);

    __syncthreads();   // buf0 (head 0) visible

    attn_head<MODE, 0>(sbuf, af, qB, oB, tv, fmh, mww, qkv_wb, qkv_w, qkv_b, l15, quad, tokg, qcl);
    __syncthreads();   // buf1 staged + buf0 reads done
    attn_head<MODE, 1>(sbuf, af, qB, oB, tv, fmh, mww, qkv_wb, qkv_w, qkv_b, l15, quad, tokg, qcl);
    __syncthreads();   // buf0 staged + buf1 reads done
    attn_head<MODE, 2>(sbuf, af, qB, oB, tv, fmh, mww, qkv_wb, qkv_w, qkv_b, l15, quad, tokg, qcl);

    // ================= Phase 4: out^T = mfma16(proj_w, O), batched+pingpong weights =================
    {
        U4 w4pf[2][6];
        f32x4 pbp[2];
        #pragma unroll
        for (int kc = 0; kc < 6; ++kc)
            ldw4<MODE>(proj_wb, proj_w, l15 * DIM + 16 * kc + quad * 4, w4pf[0][kc]);
        pbp[0] = *(const f32x4*)(proj_b + quad * 4);

        #pragma unroll
        for (int tc = 0; tc < 6; ++tc) {
            if (tc + 1 < 6) {
                #pragma unroll
                for (int kc = 0; kc < 6; ++kc)
                    ldw4<MODE>(proj_wb, proj_w, (16 * (tc + 1) + l15) * DIM + 16 * kc + quad * 4,
                               w4pf[(tc + 1) & 1][kc]);
                pbp[(tc + 1) & 1] = *(const f32x4*)(proj_b + 16 * (tc + 1) + quad * 4);
            }
            f32x4 acc[MW];
            #pragma unroll
            for (int w = 0; w < MW; ++w) acc[w] = f32x4{0.f, 0.f, 0.f, 0.f};
            #pragma unroll
            for (int kc = 0; kc < 6; ++kc)
                #pragma unroll
                for (int w = 0; w < MW; ++w)
                    acc[w] = __builtin_amdgcn_mfma_f32_16x16x16bf16_1k(
                        w4pf[tc & 1][kc].s, oB[w][kc >> 1][kc & 1].s, acc[w], 0, 0, 0);
            const f32x4 pb = pbp[tc & 1];
            #pragma unroll
            for (int w = 0; w < MW; ++w) {
                if (tokg < NTOK)
                    *(f32x4*)(out + (size_t)bw[w] * (NTOK * DIM) + tokg * DIM + 16 * tc + quad * 4) =
                        acc[w] + pb;
            }
        }
    }
}

extern "C" void kernel_launch(void* const* d_in, const int* in_sizes, int n_in,
                              void* d_out, int out_size, void* d_ws, size_t ws_size,
                              hipStream_t stream) {
    const float* x      = (const float*)d_in[0];
    const float* mask   = (const float*)d_in[1];
    const float* qkv_w  = (const float*)d_in[2];
    const float* qkv_b  = (const float*)d_in[3];
    const float* proj_w = (const float*)d_in[4];
    const float* proj_b = (const float*)d_in[5];
    const float* rpb    = (const float*)d_in[6];
    const int*   rel    = (const int*)d_in[7];
    float* outp         = (float*)d_out;

    int mode;
    if      (ws_size >= (size_t)WS_MODE2_NEED) mode = 2;
    else if (ws_size >= (size_t)WS_MODE1_NEED) mode = 1;
    else                                        mode = 0;

    unsigned short* qkv_wb  = (unsigned short*)d_ws;
    unsigned short* proj_wb = (unsigned short*)((char*)d_ws + PROJWB_OFFB);
    float* tab = (mode >= 1) ? (float*)((char*)d_ws + TAB_OFFB) : (float*)d_ws;

    const int npre = (mode == 2) ? PAD_FUSED_ELEMS
                   : (mode == 1) ? 3 * DIM * DIM
                                 : BIAS_TAB_ELEMS;
    prep<<<(npre + 255) / 256, 256, 0, stream>>>(rpb, rel, mask, qkv_w, proj_w,
                                                 qkv_wb, proj_wb, tab, mode);

    const int n_windows = in_sizes[0] / (NTOK * DIM);   // 4096
    const int nb = (n_windows + MW - 1) / MW;
    if (mode == 2)
        winattn<2><<<nb, 256, 0, stream>>>(x, mask, qkv_w, qkv_b, proj_w, proj_b,
                                           qkv_wb, proj_wb, tab, outp, n_windows);
    else if (mode == 1)
        winattn<1><<<nb, 256, 0, stream>>>(x, mask, qkv_w, qkv_b, proj_w, proj_b,
                                           qkv_wb, proj_wb, tab, outp, n_windows);
    else
        winattn<0><<<nb, 256, 0, stream>>>(x, mask, qkv_w, qkv_b, proj_w, proj_b,
                                           qkv_wb, proj_wb, tab, outp, n_windows);
}